// Round 1
// baseline (61.754 us; speedup 1.0000x reference)
//
#include <hip/hip_runtime.h>

// ParabolicPool2D: out[b,c,i,j] = max_{p,q} f[b,c,2i+p,2j+q] - z[p,q]*t[c]
// z = [[1,.5,1],[.5,0,.5],[1,.5,1]]
// B=16, C=256, H=W=128, ks=3, stride=2 -> oH=oW=63

#define C_DIM 256
#define H_DIM 128
#define W_DIM 128
#define OH 63
#define OW 63

__global__ __launch_bounds__(256) void parab_pool_kernel(
    const float* __restrict__ f,
    const float* __restrict__ t,
    float* __restrict__ out,
    int total)
{
    int idx = blockIdx.x * blockDim.x + threadIdx.x;
    if (idx >= total) return;

    int j   = idx % OW;
    int tmp = idx / OW;
    int i   = tmp % OH;
    int bc  = tmp / OH;          // b*C + c
    int c   = bc % C_DIM;

    const float a = -t[c];       // corner offset; edge offset = 0.5*a; center = 0

    const float* base = f + ((bc * H_DIM + 2 * i) * W_DIM + 2 * j);

    float r00 = base[0];
    float r01 = base[1];
    float r02 = base[2];
    float r10 = base[W_DIM + 0];
    float r11 = base[W_DIM + 1];
    float r12 = base[W_DIM + 2];
    float r20 = base[2 * W_DIM + 0];
    float r21 = base[2 * W_DIM + 1];
    float r22 = base[2 * W_DIM + 2];

    float corners = fmaxf(fmaxf(r00, r02), fmaxf(r20, r22));
    float edges   = fmaxf(fmaxf(r01, r10), fmaxf(r12, r21));

    float v = fmaxf(r11, fmaxf(corners + a, edges + 0.5f * a));
    out[idx] = v;
}

extern "C" void kernel_launch(void* const* d_in, const int* in_sizes, int n_in,
                              void* d_out, int out_size, void* d_ws, size_t ws_size,
                              hipStream_t stream)
{
    const float* f = (const float*)d_in[0];
    const float* t = (const float*)d_in[1];
    float* out = (float*)d_out;

    int total = out_size;  // 16*256*63*63
    int block = 256;
    int grid = (total + block - 1) / block;

    parab_pool_kernel<<<grid, block, 0, stream>>>(f, t, out, total);
}